// Round 8
// baseline (54.851 us; speedup 1.0000x reference)
//
#include <hip/hip_runtime.h>

#define CIN  256
#define COUT 256
#define BSZ  2
#define HH   48
#define WW   48
#define S    (HH * WW)   // 2304
#define KWIN 7

typedef short  short8 __attribute__((ext_vector_type(8)));
typedef float  f32x4  __attribute__((ext_vector_type(4)));

__device__ inline unsigned cvt_pk_bf16(float f0, float f1) {
    unsigned r;
    asm("v_cvt_pk_bf16_f32 %0, %1, %2" : "=v"(r) : "v"(f0), "v"(f1));
    return r;   // low16 = bf16(f0), high16 = bf16(f1), RNE
}

// ---------- MFMA QKV: D[s][o] = sum_c X[c][s] * W[o][c] ----------
// Block = 32(s) x 128(o) x one (b,m); 4 waves of 32s x 32o. K = 256.
// A (x tile) staged once per block into LDS as bf16 hi + lo residual (32 KB ->
// ~5 blocks/CU). B converted in-loop with v_cvt_pk_bf16_f32.
// Product = (ah + al) * bh : exact-x times bf16(w).
__global__ __launch_bounds__(256) void qkv_mfma(
    const float* __restrict__ x,              // [B][C][S]
    const float* __restrict__ wq, const float* __restrict__ wk, const float* __restrict__ wv,
    float* __restrict__ qout, float* __restrict__ kout, float* __restrict__ vout)
{
    __shared__ __align__(16) short Ahi[32][32][8];   // [c8][s][e] 16 KB
    __shared__ __align__(16) short Alo[32][32][8];   // 16 KB
    const int t    = threadIdx.x;
    const int lane = t & 63;
    const int wid  = t >> 6;
    const int r16  = lane & 15;
    const int kq   = lane >> 4;
    const int s0   = blockIdx.x * 32;
    const int o0   = blockIdx.y * 128 + wid * 32;
    const int bm   = blockIdx.z;         // b*3 + m
    const int b    = bm / 3, m = bm % 3;
    const float* wmat = (m == 0) ? wq : (m == 1 ? wk : wv);
    float* outp = ((m == 0) ? qout : (m == 1 ? kout : vout)) + (size_t)b * COUT * S;
    const float* xb = x + (size_t)b * CIN * S + s0;

    // ---- stage A: thread (ss = t&31, cg = t>>5) handles c8 = cg*4 .. cg*4+3
    const int ss = t & 31;
    const int cg = t >> 5;
#pragma unroll 2
    for (int p = 0; p < 4; ++p) {
        const int c8 = cg * 4 + p;                   // 0..31
        const float* px = xb + (size_t)(c8 * 8) * S + ss;
        float f[8];
#pragma unroll
        for (int e = 0; e < 8; ++e) f[e] = px[(size_t)e * S];
        union { unsigned u[4]; short8 v; } H, L;
#pragma unroll
        for (int pp = 0; pp < 4; ++pp) {
            H.u[pp] = cvt_pk_bf16(f[2 * pp], f[2 * pp + 1]);
            const float h0 = __uint_as_float(H.u[pp] << 16);
            const float h1 = __uint_as_float(H.u[pp] & 0xFFFF0000u);
            L.u[pp] = cvt_pk_bf16(f[2 * pp] - h0, f[2 * pp + 1] - h1);
        }
        *(short8*)&Ahi[c8][ss][0] = H.v;
        *(short8*)&Alo[c8][ss][0] = L.v;
    }
    __syncthreads();

    f32x4 acc[2][2] = {};
#pragma unroll 2
    for (int kb = 0; kb < 8; ++kb) {
        const int c8 = kb * 4 + kq;
        short8 ah[2], al[2], bh[2];
#pragma unroll
        for (int i = 0; i < 2; ++i) {
            ah[i] = *(const short8*)&Ahi[c8][i * 16 + r16][0];
            al[i] = *(const short8*)&Alo[c8][i * 16 + r16][0];
        }
#pragma unroll
        for (int j = 0; j < 2; ++j) {
            const float* pw = wmat + (size_t)(o0 + j * 16 + r16) * CIN + kb * 32 + kq * 8;
            const float4 wa = *(const float4*)pw;
            const float4 wb = *(const float4*)(pw + 4);
            union { unsigned u[4]; short8 v; } B;
            B.u[0] = cvt_pk_bf16(wa.x, wa.y);
            B.u[1] = cvt_pk_bf16(wa.z, wa.w);
            B.u[2] = cvt_pk_bf16(wb.x, wb.y);
            B.u[3] = cvt_pk_bf16(wb.z, wb.w);
            bh[j] = B.v;
        }
#pragma unroll
        for (int i = 0; i < 2; ++i)
#pragma unroll
            for (int j = 0; j < 2; ++j) {
                acc[i][j] = __builtin_amdgcn_mfma_f32_16x16x32_bf16(ah[i], bh[j], acc[i][j], 0, 0, 0);
                acc[i][j] = __builtin_amdgcn_mfma_f32_16x16x32_bf16(al[i], bh[j], acc[i][j], 0, 0, 0);
            }
    }
#pragma unroll
    for (int i = 0; i < 2; ++i)      // s subtile
#pragma unroll
        for (int j = 0; j < 2; ++j) { // o subtile
            const int o = o0 + j * 16 + r16;
            const int s = s0 + i * 16 + kq * 4;
            float4 r = make_float4(acc[i][j][0], acc[i][j][1], acc[i][j][2], acc[i][j][3]);
            *(float4*)(outp + (size_t)o * S + s) = r;
        }
}

// ---------------- Phase 2: windowed softmax-attention ----------------
// Block = 8 h-rows of one (b,o) plane, 192 thr; thread -> 2 outputs (w0, w0+1).
// LDS layout col = w+4 (rows of 60 floats, 16B-aligned): interior staged with
// aligned float4 loads/stores (420 float4 vs 1568 scalar pairs); pad cols are
// zero -> reference semantics at borders. exp2 with log2e prefolded.
__global__ __launch_bounds__(192) void attn_win(
    const float* __restrict__ qmap,   // [B*O][S] (lives in d_out)
    const float* __restrict__ kmap,
    const float* __restrict__ vmap,
    const float* __restrict__ rel_h,
    const float* __restrict__ rel_w,
    float* __restrict__ out)          // same buffer as qmap
{
    __shared__ __align__(16) float Ks[14][60];
    __shared__ __align__(16) float Vs[14][60];
    const int t  = threadIdx.x;
    const int h0 = blockIdx.x * 8;
    const int bo = blockIdx.y;
    const int o  = bo & 255;
    const float* kp = kmap + (size_t)bo * S;
    const float* vp = vmap + (size_t)bo * S;

    // 420 float4 stores: a = K/V, row 0..13, c4 0..14; c4 0,13,14 are zero pads,
    // c4 1..12 carry w = (c4-1)*4 .. +3 at col 4*c4; rows outside plane -> zeros.
    const float4 z4 = make_float4(0.f, 0.f, 0.f, 0.f);
    for (int i = t; i < 420; i += 192) {
        const int a   = (i >= 210);
        const int j   = i - 210 * a;
        const int row = j / 15;
        const int c4  = j - row * 15;
        const int hh  = h0 - 3 + row;
        const bool ok = (c4 >= 1) && (c4 <= 12) && ((unsigned)hh < (unsigned)HH);
        const float* src = a ? vp : kp;
        const float4 val = ok ? *(const float4*)(src + hh * WW + (c4 - 1) * 4) : z4;
        float* dst = a ? &Vs[row][c4 * 4] : &Ks[row][c4 * 4];
        *(float4*)dst = val;
    }

    const int w0 = (t % 24) * 2;     // outputs w0, w0+1
    const int r  = t / 24;           // 0..7
    const int h  = h0 + r;
    const float2 q2 = *(const float2*)(qmap + (size_t)bo * S + h * WW + w0);
    const float qe0 = q2.x * 1.44269504088896340736f;
    const float qe1 = q2.y * 1.44269504088896340736f;
    const bool ish = (o < 128);
    const float* rp = ish ? (rel_h + o * 7) : (rel_w + (o - 128) * 7);
    float rel[7], qr0[7], qr1[7];
#pragma unroll
    for (int i = 0; i < 7; ++i) {
        rel[i] = rp[i];
        qr0[i] = qe0 * rel[i];
        qr1[i] = qe1 * rel[i];
    }

    __syncthreads();

    float l0 = 0.f, l1 = 0.f, a0 = 0.f, a1 = 0.f;
#pragma unroll
    for (int kh = 0; kh < KWIN; ++kh) {
        const int rr = r + kh;
        // window cols: outputs w0,w0+1 need w in [w0-3, w0+4] -> LDS cols w0+1..w0+8
        float k8[8], v8[8];
#pragma unroll
        for (int n = 0; n < 8; ++n) {
            k8[n] = Ks[rr][w0 + 1 + n];
            v8[n] = Vs[rr][w0 + 1 + n];
        }
        if (ish) {
            const float b0 = qr0[kh];
            const float b1 = qr1[kh];
#pragma unroll
            for (int kw = 0; kw < KWIN; ++kw) {
                const float p0 = __builtin_amdgcn_exp2f(fmaf(qe0, k8[kw], b0));
                l0 += p0; a0 = fmaf(p0, v8[kw], a0);
                const float p1 = __builtin_amdgcn_exp2f(fmaf(qe1, k8[kw + 1], b1));
                l1 += p1; a1 = fmaf(p1, v8[kw + 1], a1);
            }
        } else {
#pragma unroll
            for (int kw = 0; kw < KWIN; ++kw) {
                const float p0 = __builtin_amdgcn_exp2f(fmaf(qe0, k8[kw], qr0[kw]));
                l0 += p0; a0 = fmaf(p0, v8[kw], a0);
                const float p1 = __builtin_amdgcn_exp2f(fmaf(qe1, k8[kw + 1], qr1[kw]));
                l1 += p1; a1 = fmaf(p1, v8[kw + 1], a1);
            }
        }
    }
    float r0, r1;
    asm("v_rcp_f32 %0, %1" : "=v"(r0) : "v"(l0));
    asm("v_rcp_f32 %0, %1" : "=v"(r1) : "v"(l1));
    float2 ov = make_float2(a0 * r0, a1 * r1);
    *(float2*)(out + (size_t)bo * S + h * WW + w0) = ov;
}

extern "C" void kernel_launch(void* const* d_in, const int* in_sizes, int n_in,
                              void* d_out, int out_size, void* d_ws, size_t ws_size,
                              hipStream_t stream) {
    const float* x     = (const float*)d_in[0];
    const float* wq    = (const float*)d_in[1];
    const float* wk    = (const float*)d_in[2];
    const float* wv    = (const float*)d_in[3];
    const float* rel_h = (const float*)d_in[4];
    const float* rel_w = (const float*)d_in[5];
    float* out  = (float*)d_out;

    float* kbuf = (float*)d_ws;                             // [B][O][S] f32
    float* vbuf = kbuf + (size_t)BSZ * COUT * S;            // [B][O][S] f32

    dim3 gg(S / 32, COUT / 128, BSZ * 3);                   // (72,2,6)
    qkv_mfma<<<gg, 256, 0, stream>>>(x, wq, wk, wv, out, kbuf, vbuf);

    dim3 g2(HH / 8, BSZ * COUT);                            // (6,512)
    attn_win<<<g2, 192, 0, stream>>>(out, kbuf, vbuf, rel_h, rel_w, out);
}

// Round 9
// 37.224 us; speedup vs baseline: 1.4736x; 1.4736x over previous
//
#include <hip/hip_runtime.h>

#define CIN  256
#define COUT 256
#define BSZ  2
#define HH   48
#define WW   48
#define S    (HH * WW)   // 2304
#define KWIN 7

typedef short  short8 __attribute__((ext_vector_type(8)));
typedef float  f32x4  __attribute__((ext_vector_type(4)));
typedef float  f32x2  __attribute__((ext_vector_type(2)));

__device__ inline unsigned cvt_pk_bf16(float f0, float f1) {
    unsigned r;
    asm("v_cvt_pk_bf16_f32 %0, %1, %2" : "=v"(r) : "v"(f0), "v"(f1));
    return r;   // low16 = bf16(f0), high16 = bf16(f1), RNE
}

// ---------- MFMA QKV: D[s][o] = sum_c X[c][s] * W[o][c] ----------
// (identical to the 37.7 us round) Block = 64(s) x 128(o) x one (b,m); 4 waves
// of 64s x 32o. K = 256. A staged once per block into LDS as bf16 hi + lo
// residual; B converted in-loop with v_cvt_pk_bf16_f32.
// Product = (ah + al) * bh : exact-x times bf16(w).
__global__ __launch_bounds__(256) void qkv_mfma(
    const float* __restrict__ x,              // [B][C][S]
    const float* __restrict__ wq, const float* __restrict__ wk, const float* __restrict__ wv,
    float* __restrict__ qout, float* __restrict__ kout, float* __restrict__ vout)
{
    __shared__ __align__(16) short Ahi[32][64][8];   // [c8][s][e] 32 KB
    __shared__ __align__(16) short Alo[32][64][8];   // 32 KB
    const int t    = threadIdx.x;
    const int lane = t & 63;
    const int wid  = t >> 6;
    const int r16  = lane & 15;
    const int kq   = lane >> 4;
    const int s0   = blockIdx.x * 64;
    const int o0   = blockIdx.y * 128 + wid * 32;
    const int bm   = blockIdx.z;         // b*3 + m
    const int b    = bm / 3, m = bm % 3;
    const float* wmat = (m == 0) ? wq : (m == 1 ? wk : wv);
    float* outp = ((m == 0) ? qout : (m == 1 ? kout : vout)) + (size_t)b * COUT * S;
    const float* xb = x + (size_t)b * CIN * S + s0;

    // ---- stage A: thread (ss = t&63, cg = t>>6) handles c-chunks cg, cg+4, ..., cg+28
    const int ss = t & 63;
    const int cg = t >> 6;
#pragma unroll 2
    for (int p = 0; p < 8; ++p) {
        const int c8 = cg + p * 4;                   // 0..31
        const float* px = xb + (size_t)(c8 * 8) * S + ss;
        float f[8];
#pragma unroll
        for (int e = 0; e < 8; ++e) f[e] = px[(size_t)e * S];
        union { unsigned u[4]; short8 v; } H, L;
#pragma unroll
        for (int pp = 0; pp < 4; ++pp) {
            H.u[pp] = cvt_pk_bf16(f[2 * pp], f[2 * pp + 1]);
            const float h0 = __uint_as_float(H.u[pp] << 16);
            const float h1 = __uint_as_float(H.u[pp] & 0xFFFF0000u);
            L.u[pp] = cvt_pk_bf16(f[2 * pp] - h0, f[2 * pp + 1] - h1);
        }
        *(short8*)&Ahi[c8][ss][0] = H.v;
        *(short8*)&Alo[c8][ss][0] = L.v;
    }
    __syncthreads();

    f32x4 acc[4][2] = {};
#pragma unroll 2
    for (int kb = 0; kb < 8; ++kb) {
        const int c8 = kb * 4 + kq;
        short8 ah[4], al[4], bh[2];
#pragma unroll
        for (int i = 0; i < 4; ++i) {
            ah[i] = *(const short8*)&Ahi[c8][i * 16 + r16][0];
            al[i] = *(const short8*)&Alo[c8][i * 16 + r16][0];
        }
#pragma unroll
        for (int j = 0; j < 2; ++j) {
            const float* pw = wmat + (size_t)(o0 + j * 16 + r16) * CIN + kb * 32 + kq * 8;
            const float4 wa = *(const float4*)pw;
            const float4 wb = *(const float4*)(pw + 4);
            union { unsigned u[4]; short8 v; } B;
            B.u[0] = cvt_pk_bf16(wa.x, wa.y);
            B.u[1] = cvt_pk_bf16(wa.z, wa.w);
            B.u[2] = cvt_pk_bf16(wb.x, wb.y);
            B.u[3] = cvt_pk_bf16(wb.z, wb.w);
            bh[j] = B.v;
        }
#pragma unroll
        for (int i = 0; i < 4; ++i)
#pragma unroll
            for (int j = 0; j < 2; ++j) {
                acc[i][j] = __builtin_amdgcn_mfma_f32_16x16x32_bf16(ah[i], bh[j], acc[i][j], 0, 0, 0);
                acc[i][j] = __builtin_amdgcn_mfma_f32_16x16x32_bf16(al[i], bh[j], acc[i][j], 0, 0, 0);
            }
    }
#pragma unroll
    for (int i = 0; i < 4; ++i)      // s subtile
#pragma unroll
        for (int j = 0; j < 2; ++j) { // o subtile
            const int o = o0 + j * 16 + r16;
            const int s = s0 + i * 16 + kq * 4;
            float4 r = make_float4(acc[i][j][0], acc[i][j][1], acc[i][j][2], acc[i][j][3]);
            *(float4*)(outp + (size_t)o * S + s) = r;
        }
}

// ---------------- Phase 2: windowed softmax-attention ----------------
// Structure of the 37.7 us round (8 h-rows, 192 thr, 2 outputs/thread, col=w+3
// layout, aligned float2 window reads) + two deltas: (1) qe*rel hoisted,
// (2) score/accumulate chain as float2 ext-vectors -> v_pk_fma_f32/v_pk_add_f32.
__global__ __launch_bounds__(192) void attn_win(
    const float* __restrict__ qmap,   // [B*O][S] (lives in d_out)
    const float* __restrict__ kmap,
    const float* __restrict__ vmap,
    const float* __restrict__ rel_h,
    const float* __restrict__ rel_w,
    float* __restrict__ out)          // same buffer as qmap
{
    __shared__ __align__(16) float Ks[14][60];
    __shared__ __align__(16) float Vs[14][60];
    const int t  = threadIdx.x;
    const int h0 = blockIdx.x * 8;
    const int bo = blockIdx.y;
    const int o  = bo & 255;
    const float* kp = kmap + (size_t)bo * S;
    const float* vp = vmap + (size_t)bo * S;

    for (int i = t; i < 14 * 56; i += 192) {
        const int row = i / 56, col = i - row * 56;
        const int hh = h0 - 3 + row, ww = col - 3;
        const bool ok = ((unsigned)hh < (unsigned)HH) && ((unsigned)ww < (unsigned)WW);
        Ks[row][col] = ok ? kp[hh * WW + ww] : 0.f;
        Vs[row][col] = ok ? vp[hh * WW + ww] : 0.f;
    }

    const int w0 = (t % 24) * 2;     // outputs w0, w0+1
    const int r  = t / 24;           // 0..7
    const int h  = h0 + r;
    const float2 q2 = *(const float2*)(qmap + (size_t)bo * S + h * WW + w0);
    const float qe0 = q2.x * 1.44269504088896340736f;
    const float qe1 = q2.y * 1.44269504088896340736f;
    const f32x2 qe2 = {qe0, qe1};
    const bool ish = (o < 128);
    const float* rp = ish ? (rel_h + o * 7) : (rel_w + (o - 128) * 7);
    f32x2 qr[7];
#pragma unroll
    for (int i = 0; i < 7; ++i) {
        const float rv = rp[i];
        qr[i] = (f32x2){qe0 * rv, qe1 * rv};
    }

    __syncthreads();

    f32x2 l2 = {0.f, 0.f}, a2 = {0.f, 0.f};
#pragma unroll
    for (int kh = 0; kh < KWIN; ++kh) {
        const int rr = r + kh;
        float k8[8], v8[8];
#pragma unroll
        for (int n = 0; n < 4; ++n) {
            *(float2*)&k8[2 * n] = *(const float2*)&Ks[rr][w0 + 2 * n];
            *(float2*)&v8[2 * n] = *(const float2*)&Vs[rr][w0 + 2 * n];
        }
        if (ish) {
            const f32x2 b2 = qr[kh];
#pragma unroll
            for (int kw = 0; kw < KWIN; ++kw) {
                const f32x2 kk = {k8[kw], k8[kw + 1]};
                const f32x2 vv = {v8[kw], v8[kw + 1]};
                const f32x2 sc = __builtin_elementwise_fma(qe2, kk, b2);
                f32x2 p;
                p.x = __builtin_amdgcn_exp2f(sc.x);
                p.y = __builtin_amdgcn_exp2f(sc.y);
                l2 += p;
                a2 = __builtin_elementwise_fma(p, vv, a2);
            }
        } else {
#pragma unroll
            for (int kw = 0; kw < KWIN; ++kw) {
                const f32x2 kk = {k8[kw], k8[kw + 1]};
                const f32x2 vv = {v8[kw], v8[kw + 1]};
                const f32x2 sc = __builtin_elementwise_fma(qe2, kk, qr[kw]);
                f32x2 p;
                p.x = __builtin_amdgcn_exp2f(sc.x);
                p.y = __builtin_amdgcn_exp2f(sc.y);
                l2 += p;
                a2 = __builtin_elementwise_fma(p, vv, a2);
            }
        }
    }
    float r0, r1;
    asm("v_rcp_f32 %0, %1" : "=v"(r0) : "v"(l2.x));
    asm("v_rcp_f32 %0, %1" : "=v"(r1) : "v"(l2.y));
    float2 ov = make_float2(a2.x * r0, a2.y * r1);
    *(float2*)(out + (size_t)bo * S + h * WW + w0) = ov;
}

extern "C" void kernel_launch(void* const* d_in, const int* in_sizes, int n_in,
                              void* d_out, int out_size, void* d_ws, size_t ws_size,
                              hipStream_t stream) {
    const float* x     = (const float*)d_in[0];
    const float* wq    = (const float*)d_in[1];
    const float* wk    = (const float*)d_in[2];
    const float* wv    = (const float*)d_in[3];
    const float* rel_h = (const float*)d_in[4];
    const float* rel_w = (const float*)d_in[5];
    float* out  = (float*)d_out;

    float* kbuf = (float*)d_ws;                             // [B][O][S] f32
    float* vbuf = kbuf + (size_t)BSZ * COUT * S;            // [B][O][S] f32

    dim3 gg(S / 64, COUT / 128, BSZ * 3);                   // (36,2,6)
    qkv_mfma<<<gg, 256, 0, stream>>>(x, wq, wk, wv, out, kbuf, vbuf);

    dim3 g2(HH / 8, BSZ * COUT);                            // (6,512)
    attn_win<<<g2, 192, 0, stream>>>(out, kbuf, vbuf, rel_h, rel_w, out);
}